// Round 7
// baseline (2245.551 us; speedup 1.0000x reference)
//
#include <hip/hip_runtime.h>
#include <cstddef>

// ---------------------------------------------------------------------------
// embed+concat -> Linear(80->96) -> 3x SAGEConv(96, mean) -> MLP(96->256->256->1)
// fp32. N = in_sizes[1], E = in_sizes[2]/2.
// Round 6: k-chunked XOR-swizzled LDS layout (float4 slots). Conflict-free
// ds_write_b128 staging + b128 fragment reads; stride-16 row/col ownership;
// TM=8 micro-tiles. Fusions unchanged from round 3/5.
// ---------------------------------------------------------------------------

#define NB 256

// ---- CSR: count in-degree --------------------------------------------------
__global__ __launch_bounds__(NB) void count_int_kernel(const int* __restrict__ dst,
                                                       int* __restrict__ cnt, int E) {
    int e = blockIdx.x * NB + threadIdx.x;
    if (e < E) atomicAdd(&cnt[dst[e]], 1);
}

// ---- CSR: single-block exclusive scan --------------------------------------
__global__ __launch_bounds__(1024) void scan_kernel(const int* __restrict__ cnt,
                                                    int* __restrict__ rowptr,
                                                    int* __restrict__ cursor, int n) {
    __shared__ int buf[1024];
    __shared__ int carry;
    const int tid = threadIdx.x;
    if (tid == 0) carry = 0;
    __syncthreads();
    const int CH = 1024 * 8;
    for (int base = 0; base < n; base += CH) {
        int loc[8];
        int s = 0;
        #pragma unroll
        for (int q = 0; q < 8; ++q) {
            int i = base + tid * 8 + q;
            int v = (i < n) ? cnt[i] : 0;
            loc[q] = s;
            s += v;
        }
        buf[tid] = s;
        __syncthreads();
        for (int off = 1; off < 1024; off <<= 1) {
            int t = (tid >= off) ? buf[tid - off] : 0;
            __syncthreads();
            buf[tid] += t;
            __syncthreads();
        }
        int tpref = carry + buf[tid] - s;
        #pragma unroll
        for (int q = 0; q < 8; ++q) {
            int i = base + tid * 8 + q;
            if (i < n) {
                int v = tpref + loc[q];
                rowptr[i] = v;
                cursor[i] = v;
            }
        }
        int chunk = buf[1023];
        __syncthreads();
        if (tid == 0) carry += chunk;
        __syncthreads();
    }
    if (tid == 0) rowptr[n] = carry;
}

// ---- CSR: fill column (src) list -------------------------------------------
__global__ __launch_bounds__(NB) void fill_csr_kernel(const int* __restrict__ src,
                                                      const int* __restrict__ dst,
                                                      int* __restrict__ cursor,
                                                      int* __restrict__ col, int E) {
    int e = blockIdx.x * NB + threadIdx.x;
    if (e >= E) return;
    int p = atomicAdd(&cursor[dst[e]], 1);
    col[p] = src[e];
}

// ---- gather-mean: G[n] = mean_{j in col[rowptr[n]:rowptr[n+1]]} X[j] -------
__global__ __launch_bounds__(NB) void gather_mean_kernel(
    const float* __restrict__ X, const int* __restrict__ rowptr,
    const int* __restrict__ col, float* __restrict__ G, int N) {
    int idx = blockIdx.x * NB + threadIdx.x;
    int node = idx / 24;
    if (node >= N) return;
    int c = idx - node * 24;
    const int s = rowptr[node], pe = rowptr[node + 1];
    float4 acc = {0.f, 0.f, 0.f, 0.f};
    int p = s;
    for (; p + 3 < pe; p += 4) {
        int j0 = col[p], j1 = col[p + 1], j2 = col[p + 2], j3 = col[p + 3];
        float4 v0 = *reinterpret_cast<const float4*>(&X[(size_t)j0 * 96 + 4 * c]);
        float4 v1 = *reinterpret_cast<const float4*>(&X[(size_t)j1 * 96 + 4 * c]);
        float4 v2 = *reinterpret_cast<const float4*>(&X[(size_t)j2 * 96 + 4 * c]);
        float4 v3 = *reinterpret_cast<const float4*>(&X[(size_t)j3 * 96 + 4 * c]);
        acc.x += (v0.x + v1.x) + (v2.x + v3.x);
        acc.y += (v0.y + v1.y) + (v2.y + v3.y);
        acc.z += (v0.z + v1.z) + (v2.z + v3.z);
        acc.w += (v0.w + v1.w) + (v2.w + v3.w);
    }
    for (; p < pe; ++p) {
        int j = col[p];
        float4 v = *reinterpret_cast<const float4*>(&X[(size_t)j * 96 + 4 * c]);
        acc.x += v.x; acc.y += v.y; acc.z += v.z; acc.w += v.w;
    }
    int deg = pe - s;
    float inv = (deg > 0) ? 1.f / (float)deg : 0.f;
    acc.x *= inv; acc.y *= inv; acc.z *= inv; acc.w *= inv;
    *reinterpret_cast<float4*>(&G[(size_t)node * 96 + 4 * c]) = acc;
}

// ---- register-tiled GEMM, k-chunked swizzled LDS ---------------------------
// LDS: Xs[q][m] = float4 {X[m][4q..4q+3]} stored at slot q*BM + (m ^ q).
// Staging: lane (q=v%QX, m=v/QX) -> coalesced global float4, 1 ds_write_b128,
//          wave's 64 slots cover all 32 banks once (conflict-free).
// Compute: thread (tx,ty) owns rows ty+16*i, cols tx+16*j.
//          a4[i] = Xs slot (q, row^q)  (4 k-values, one b128)
//          b4[j] = Ws slot (q, col^q)
// EMB: X-load gathers embeddings. FDOT: out[r] += relu(row).d2w (atomicAdd).
// Grid 1D, col-tile fastest.
template <int K, int OUT, int BM, int BN, int TM, int TN, int BK,
          bool RELU, bool SAGE, bool EMB, bool FDOT>
__global__ __launch_bounds__(NB) void gemm3(
    const float* __restrict__ X, const float* __restrict__ G,
    const float* __restrict__ Wx, const float* __restrict__ Wg,
    const float* __restrict__ bias,
    const int* __restrict__ xl, const int* __restrict__ xr,
    const float* __restrict__ lemb, const float* __restrict__ remb,
    const float* __restrict__ d2w, const float* __restrict__ d2b,
    float* __restrict__ Y, int nrows) {
    constexpr int QX = BK / 4;        // k-chunks per BK step
    constexpr int CT = OUT / BN;      // col tiles
    constexpr int KT = SAGE ? 2 * K : K;
    __shared__ float4 Xs[QX * BM];
    __shared__ float4 Ws[QX * BN];

    const int t = threadIdx.x;
    const int tx = t & 15, ty = t >> 4;
    const int bid = blockIdx.x;
    const int rowBase = (bid / CT) * BM;
    const int colTile = bid % CT;
    const int colBase = colTile * BN;

    float acc[TM][TN];
#pragma unroll
    for (int i = 0; i < TM; ++i)
#pragma unroll
        for (int j = 0; j < TN; ++j) acc[i][j] = 0.f;

    for (int k0 = 0; k0 < KT; k0 += BK) {
        const bool isG = SAGE && (k0 >= K);
        const float* __restrict__ Xp = isG ? G : X;
        const float* __restrict__ Wp = isG ? Wg : Wx;
        const int kl = isG ? (k0 - K) : k0;

        // ---- stage X tile: q fast across lanes (coalesced), swizzled write
        for (int v = t; v < BM * QX; v += NB) {
            int q = v % QX, m = v / QX;
            int r = rowBase + m;
            float4 f = {0.f, 0.f, 0.f, 0.f};
            if (r < nrows) {
                if (EMB) {
                    int kk = kl + 4 * q;
                    if (kk < 64) {
                        int l = kk >> 4, c = kk & 15;
                        f = *reinterpret_cast<const float4*>(
                            &lemb[(size_t)xl[r * 4 + l] * 16 + c]);
                    } else {
                        f = *reinterpret_cast<const float4*>(
                            &remb[(size_t)xr[r] * 16 + (kk - 64)]);
                    }
                } else {
                    f = *reinterpret_cast<const float4*>(&Xp[(size_t)r * K + kl + 4 * q]);
                }
            }
            Xs[q * BM + (m ^ q)] = f;
        }
        // ---- stage W tile
        for (int v = t; v < BN * QX; v += NB) {
            int q = v % QX, n = v / QX;
            float4 f = *reinterpret_cast<const float4*>(
                &Wp[(size_t)(colBase + n) * K + kl + 4 * q]);
            Ws[q * BN + (n ^ q)] = f;
        }
        __syncthreads();

#pragma unroll
        for (int q = 0; q < QX; ++q) {
            float4 a4[TM], b4[TN];
#pragma unroll
            for (int i = 0; i < TM; ++i)
                a4[i] = Xs[q * BM + ((ty + 16 * i) ^ q)];
#pragma unroll
            for (int j = 0; j < TN; ++j)
                b4[j] = Ws[q * BN + ((tx + 16 * j) ^ q)];
#pragma unroll
            for (int i = 0; i < TM; ++i)
#pragma unroll
                for (int j = 0; j < TN; ++j) {
                    acc[i][j] += a4[i].x * b4[j].x + a4[i].y * b4[j].y +
                                 a4[i].z * b4[j].z + a4[i].w * b4[j].w;
                }
        }
        __syncthreads();
    }

    if (!FDOT) {
#pragma unroll
        for (int i = 0; i < TM; ++i) {
            int r = rowBase + ty + 16 * i;
            if (r >= nrows) continue;
#pragma unroll
            for (int j = 0; j < TN; ++j) {
                int c = colBase + tx + 16 * j;
                float v = acc[i][j] + bias[c];
                if (RELU) v = fmaxf(v, 0.f);
                Y[(size_t)r * OUT + c] = v;
            }
        }
    } else {
#pragma unroll
        for (int i = 0; i < TM; ++i) {
            int r = rowBase + ty + 16 * i;
            float p = 0.f;
#pragma unroll
            for (int j = 0; j < TN; ++j) {
                int c = colBase + tx + 16 * j;
                float v = fmaxf(acc[i][j] + bias[c], 0.f);
                p += v * d2w[c];
            }
#pragma unroll
            for (int off = 1; off < 16; off <<= 1) p += __shfl_xor(p, off);
            if (tx == 0 && r < nrows)
                atomicAdd(&Y[r], p + (colTile == 0 ? d2b[0] : 0.f));
        }
    }
}

// ---------------------------------------------------------------------------
extern "C" void kernel_launch(void* const* d_in, const int* in_sizes, int n_in,
                              void* d_out, int out_size, void* d_ws, size_t ws_size,
                              hipStream_t stream) {
    const int*   x_layout = (const int*)d_in[0];
    const int*   x_role   = (const int*)d_in[1];
    const int*   ei       = (const int*)d_in[2];
    const float* lemb     = (const float*)d_in[3];
    const float* remb     = (const float*)d_in[4];
    const float* lin_W    = (const float*)d_in[5];
    const float* lin_b    = (const float*)d_in[6];
    const float* c0_lW    = (const float*)d_in[7];
    const float* c0_lb    = (const float*)d_in[8];
    const float* c0_rW    = (const float*)d_in[9];
    const float* c1_lW    = (const float*)d_in[10];
    const float* c1_lb    = (const float*)d_in[11];
    const float* c1_rW    = (const float*)d_in[12];
    const float* c2_lW    = (const float*)d_in[13];
    const float* c2_lb    = (const float*)d_in[14];
    const float* c2_rW    = (const float*)d_in[15];
    const float* d0_W     = (const float*)d_in[16];
    const float* d0_b     = (const float*)d_in[17];
    const float* d1_W     = (const float*)d_in[18];
    const float* d1_b     = (const float*)d_in[19];
    const float* d2_W     = (const float*)d_in[20];
    const float* d2_b     = (const float*)d_in[21];

    const int N = in_sizes[1];
    const int E = in_sizes[2] / 2;
    const int* src = ei;
    const int* dst = ei + E;

    // workspace (4-byte elems):
    //   R0 (256N): early = [rowptr(N+1)|cursor(N)|col(E)]; late = H0(256N)
    //   then A(96N) | B(96N) | C(96N)
    float* ws     = (float*)d_ws;
    float* H0     = ws;
    int*   rowptr = (int*)d_ws;
    int*   cursor = rowptr + (N + 1);
    int*   col    = cursor + N;
    float* A      = ws + (size_t)256 * N;
    float* B      = A + (size_t)96 * N;
    float* C      = B + (size_t)96 * N;

    const dim3 blk(NB);
    const int rt128 = (N + 127) / 128;
    const dim3 gE((E + NB - 1) / NB);
    const dim3 gGather(((size_t)N * 24 + NB - 1) / NB);

    // ---- CSR build ----
    hipMemsetAsync(cursor, 0, (size_t)N * sizeof(int), stream);
    count_int_kernel<<<gE, blk, 0, stream>>>(dst, cursor, E);
    scan_kernel<<<dim3(1), dim3(1024), 0, stream>>>(cursor, rowptr, cursor, N);
    fill_csr_kernel<<<gE, blk, 0, stream>>>(src, dst, cursor, col, E);

    // ---- embed + lin -> A (embedding fused; K=80 -> BK=16) ----
    gemm3<80, 96, 128, 96, 8, 6, 16, false, false, true, false>
        <<<dim3(rt128), blk, 0, stream>>>(
        nullptr, nullptr, lin_W, nullptr, lin_b,
        x_layout, x_role, lemb, remb, nullptr, nullptr, A, N);

    // ---- layer 0: A -> C ----
    gather_mean_kernel<<<gGather, blk, 0, stream>>>(A, rowptr, col, B, N);
    gemm3<96, 96, 128, 96, 8, 6, 32, true, true, false, false>
        <<<dim3(rt128), blk, 0, stream>>>(
        A, B, c0_rW, c0_lW, c0_lb, nullptr, nullptr, nullptr, nullptr,
        nullptr, nullptr, C, N);

    // ---- layer 1: C -> A ----
    gather_mean_kernel<<<gGather, blk, 0, stream>>>(C, rowptr, col, B, N);
    gemm3<96, 96, 128, 96, 8, 6, 32, true, true, false, false>
        <<<dim3(rt128), blk, 0, stream>>>(
        C, B, c1_rW, c1_lW, c1_lb, nullptr, nullptr, nullptr, nullptr,
        nullptr, nullptr, A, N);

    // ---- layer 2: A -> C ----
    gather_mean_kernel<<<gGather, blk, 0, stream>>>(A, rowptr, col, B, N);
    gemm3<96, 96, 128, 96, 8, 6, 32, true, true, false, false>
        <<<dim3(rt128), blk, 0, stream>>>(
        A, B, c2_rW, c2_lW, c2_lb, nullptr, nullptr, nullptr, nullptr,
        nullptr, nullptr, C, N);

    // ---- head: d0 (C -> H0), then d1+d2 fused (H0 -> out) ----
    gemm3<96, 256, 128, 128, 8, 8, 32, true, false, false, false>
        <<<dim3(rt128 * 2), blk, 0, stream>>>(
        C, nullptr, d0_W, nullptr, d0_b, nullptr, nullptr, nullptr, nullptr,
        nullptr, nullptr, H0, N);

    hipMemsetAsync(d_out, 0, (size_t)N * sizeof(float), stream);
    gemm3<256, 256, 128, 128, 8, 8, 32, true, false, false, true>
        <<<dim3(rt128 * 2), blk, 0, stream>>>(
        H0, nullptr, d1_W, nullptr, d1_b, nullptr, nullptr, nullptr, nullptr,
        d2_W, d2_b, (float*)d_out, N);
}

// Round 8
// 1013.202 us; speedup vs baseline: 2.2163x; 2.2163x over previous
//
#include <hip/hip_runtime.h>
#include <cstddef>

// ---------------------------------------------------------------------------
// embed+concat -> Linear(80->96) -> 3x SAGEConv(96, mean) -> MLP(96->256->256->1)
// fp32. N = in_sizes[1], E = in_sizes[2]/2.
// Round 8: swizzled float4-slot LDS (conflict-free, r7-verified) + carry-free
// XOR rewrite (ty^q)+16i so fragment reads are base+imm ds_read_b128, and
// TM=4 micro-tiles (r6-proven VGPR budget). Fusions unchanged.
// ---------------------------------------------------------------------------

#define NB 256

// ---- CSR: count in-degree --------------------------------------------------
__global__ __launch_bounds__(NB) void count_int_kernel(const int* __restrict__ dst,
                                                       int* __restrict__ cnt, int E) {
    int e = blockIdx.x * NB + threadIdx.x;
    if (e < E) atomicAdd(&cnt[dst[e]], 1);
}

// ---- CSR: single-block exclusive scan --------------------------------------
__global__ __launch_bounds__(1024) void scan_kernel(const int* __restrict__ cnt,
                                                    int* __restrict__ rowptr,
                                                    int* __restrict__ cursor, int n) {
    __shared__ int buf[1024];
    __shared__ int carry;
    const int tid = threadIdx.x;
    if (tid == 0) carry = 0;
    __syncthreads();
    const int CH = 1024 * 8;
    for (int base = 0; base < n; base += CH) {
        int loc[8];
        int s = 0;
        #pragma unroll
        for (int q = 0; q < 8; ++q) {
            int i = base + tid * 8 + q;
            int v = (i < n) ? cnt[i] : 0;
            loc[q] = s;
            s += v;
        }
        buf[tid] = s;
        __syncthreads();
        for (int off = 1; off < 1024; off <<= 1) {
            int t = (tid >= off) ? buf[tid - off] : 0;
            __syncthreads();
            buf[tid] += t;
            __syncthreads();
        }
        int tpref = carry + buf[tid] - s;
        #pragma unroll
        for (int q = 0; q < 8; ++q) {
            int i = base + tid * 8 + q;
            if (i < n) {
                int v = tpref + loc[q];
                rowptr[i] = v;
                cursor[i] = v;
            }
        }
        int chunk = buf[1023];
        __syncthreads();
        if (tid == 0) carry += chunk;
        __syncthreads();
    }
    if (tid == 0) rowptr[n] = carry;
}

// ---- CSR: fill column (src) list -------------------------------------------
__global__ __launch_bounds__(NB) void fill_csr_kernel(const int* __restrict__ src,
                                                      const int* __restrict__ dst,
                                                      int* __restrict__ cursor,
                                                      int* __restrict__ col, int E) {
    int e = blockIdx.x * NB + threadIdx.x;
    if (e >= E) return;
    int p = atomicAdd(&cursor[dst[e]], 1);
    col[p] = src[e];
}

// ---- gather-mean: G[n] = mean_{j in col[rowptr[n]:rowptr[n+1]]} X[j] -------
__global__ __launch_bounds__(NB) void gather_mean_kernel(
    const float* __restrict__ X, const int* __restrict__ rowptr,
    const int* __restrict__ col, float* __restrict__ G, int N) {
    int idx = blockIdx.x * NB + threadIdx.x;
    int node = idx / 24;
    if (node >= N) return;
    int c = idx - node * 24;
    const int s = rowptr[node], pe = rowptr[node + 1];
    float4 acc = {0.f, 0.f, 0.f, 0.f};
    int p = s;
    for (; p + 3 < pe; p += 4) {
        int j0 = col[p], j1 = col[p + 1], j2 = col[p + 2], j3 = col[p + 3];
        float4 v0 = *reinterpret_cast<const float4*>(&X[(size_t)j0 * 96 + 4 * c]);
        float4 v1 = *reinterpret_cast<const float4*>(&X[(size_t)j1 * 96 + 4 * c]);
        float4 v2 = *reinterpret_cast<const float4*>(&X[(size_t)j2 * 96 + 4 * c]);
        float4 v3 = *reinterpret_cast<const float4*>(&X[(size_t)j3 * 96 + 4 * c]);
        acc.x += (v0.x + v1.x) + (v2.x + v3.x);
        acc.y += (v0.y + v1.y) + (v2.y + v3.y);
        acc.z += (v0.z + v1.z) + (v2.z + v3.z);
        acc.w += (v0.w + v1.w) + (v2.w + v3.w);
    }
    for (; p < pe; ++p) {
        int j = col[p];
        float4 v = *reinterpret_cast<const float4*>(&X[(size_t)j * 96 + 4 * c]);
        acc.x += v.x; acc.y += v.y; acc.z += v.z; acc.w += v.w;
    }
    int deg = pe - s;
    float inv = (deg > 0) ? 1.f / (float)deg : 0.f;
    acc.x *= inv; acc.y *= inv; acc.z *= inv; acc.w *= inv;
    *reinterpret_cast<float4*>(&G[(size_t)node * 96 + 4 * c]) = acc;
}

// ---- register-tiled GEMM, swizzled float4-slot LDS -------------------------
// LDS slot layout: Xs[q*BM + (m^q)] = float4 {row m, k-chunk q} (q < 8, so the
// XOR only touches bits 0-2 of m). Staging: 1 coalesced global float4 ->
// 1 ds_write_b128; wave covers each bank-group 8x = b128 minimum (r7: 0 confl).
// Fragment reads: rows m = ty+16*i and (ty+16i)^q == (ty^q)+16i (no carry),
// so per-q base pointer + compile-time offset -> ds_read_b128 with imm.
// Thread (tx,ty) in 16x16 owns rows ty+16*i, cols tx+16*j.
// EMB: X-load gathers embeddings. FDOT: out[r] += relu(row).d2w (atomicAdd).
// Grid 1D, col-tile fastest.
template <int K, int OUT, int BM, int BN, int TM, int TN, int BK,
          bool RELU, bool SAGE, bool EMB, bool FDOT>
__global__ __launch_bounds__(NB) void gemm4(
    const float* __restrict__ X, const float* __restrict__ G,
    const float* __restrict__ Wx, const float* __restrict__ Wg,
    const float* __restrict__ bias,
    const int* __restrict__ xl, const int* __restrict__ xr,
    const float* __restrict__ lemb, const float* __restrict__ remb,
    const float* __restrict__ d2w, const float* __restrict__ d2b,
    float* __restrict__ Y, int nrows) {
    constexpr int QX = BK / 4;        // k-chunks per BK step (4 or 8; q < 8)
    constexpr int CT = OUT / BN;      // col tiles
    constexpr int KT = SAGE ? 2 * K : K;
    static_assert(QX <= 8, "XOR swizzle assumes q < 8");
    __shared__ float4 Xs[QX * BM];
    __shared__ float4 Ws[QX * BN];

    const int t = threadIdx.x;
    const int tx = t & 15, ty = t >> 4;
    const int bid = blockIdx.x;
    const int rowBase = (bid / CT) * BM;
    const int colTile = bid % CT;
    const int colBase = colTile * BN;

    float acc[TM][TN];
#pragma unroll
    for (int i = 0; i < TM; ++i)
#pragma unroll
        for (int j = 0; j < TN; ++j) acc[i][j] = 0.f;

    for (int k0 = 0; k0 < KT; k0 += BK) {
        const bool isG = SAGE && (k0 >= K);
        const float* __restrict__ Xp = isG ? G : X;
        const float* __restrict__ Wp = isG ? Wg : Wx;
        const int kl = isG ? (k0 - K) : k0;

        // ---- stage X tile: q fast across lanes (coalesced), swizzled slot
        for (int v = t; v < BM * QX; v += NB) {
            int q = v % QX, m = v / QX;
            int r = rowBase + m;
            float4 f = {0.f, 0.f, 0.f, 0.f};
            if (r < nrows) {
                if (EMB) {
                    int kk = kl + 4 * q;
                    if (kk < 64) {
                        int l = kk >> 4, c = kk & 15;
                        f = *reinterpret_cast<const float4*>(
                            &lemb[(size_t)xl[r * 4 + l] * 16 + c]);
                    } else {
                        f = *reinterpret_cast<const float4*>(
                            &remb[(size_t)xr[r] * 16 + (kk - 64)]);
                    }
                } else {
                    f = *reinterpret_cast<const float4*>(&Xp[(size_t)r * K + kl + 4 * q]);
                }
            }
            Xs[q * BM + (m ^ q)] = f;
        }
        // ---- stage W tile
        for (int v = t; v < BN * QX; v += NB) {
            int q = v % QX, n = v / QX;
            float4 f = *reinterpret_cast<const float4*>(
                &Wp[(size_t)(colBase + n) * K + kl + 4 * q]);
            Ws[q * BN + (n ^ q)] = f;
        }
        __syncthreads();

#pragma unroll
        for (int q = 0; q < QX; ++q) {
            // carry-free XOR: base per q, imm offsets 16*i / 16*j
            const float4* __restrict__ xa = &Xs[q * BM + (ty ^ q)];
            const float4* __restrict__ wb = &Ws[q * BN + (tx ^ q)];
            float4 a4[TM], b4[TN];
#pragma unroll
            for (int i = 0; i < TM; ++i) a4[i] = xa[16 * i];
#pragma unroll
            for (int j = 0; j < TN; ++j) b4[j] = wb[16 * j];
#pragma unroll
            for (int i = 0; i < TM; ++i)
#pragma unroll
                for (int j = 0; j < TN; ++j) {
                    acc[i][j] += a4[i].x * b4[j].x + a4[i].y * b4[j].y +
                                 a4[i].z * b4[j].z + a4[i].w * b4[j].w;
                }
        }
        __syncthreads();
    }

    if (!FDOT) {
#pragma unroll
        for (int i = 0; i < TM; ++i) {
            int r = rowBase + ty + 16 * i;
            if (r >= nrows) continue;
#pragma unroll
            for (int j = 0; j < TN; ++j) {
                int c = colBase + tx + 16 * j;
                float v = acc[i][j] + bias[c];
                if (RELU) v = fmaxf(v, 0.f);
                Y[(size_t)r * OUT + c] = v;
            }
        }
    } else {
#pragma unroll
        for (int i = 0; i < TM; ++i) {
            int r = rowBase + ty + 16 * i;
            float p = 0.f;
#pragma unroll
            for (int j = 0; j < TN; ++j) {
                int c = colBase + tx + 16 * j;
                float v = fmaxf(acc[i][j] + bias[c], 0.f);
                p += v * d2w[c];
            }
#pragma unroll
            for (int off = 1; off < 16; off <<= 1) p += __shfl_xor(p, off);
            if (tx == 0 && r < nrows)
                atomicAdd(&Y[r], p + (colTile == 0 ? d2b[0] : 0.f));
        }
    }
}

// ---------------------------------------------------------------------------
extern "C" void kernel_launch(void* const* d_in, const int* in_sizes, int n_in,
                              void* d_out, int out_size, void* d_ws, size_t ws_size,
                              hipStream_t stream) {
    const int*   x_layout = (const int*)d_in[0];
    const int*   x_role   = (const int*)d_in[1];
    const int*   ei       = (const int*)d_in[2];
    const float* lemb     = (const float*)d_in[3];
    const float* remb     = (const float*)d_in[4];
    const float* lin_W    = (const float*)d_in[5];
    const float* lin_b    = (const float*)d_in[6];
    const float* c0_lW    = (const float*)d_in[7];
    const float* c0_lb    = (const float*)d_in[8];
    const float* c0_rW    = (const float*)d_in[9];
    const float* c1_lW    = (const float*)d_in[10];
    const float* c1_lb    = (const float*)d_in[11];
    const float* c1_rW    = (const float*)d_in[12];
    const float* c2_lW    = (const float*)d_in[13];
    const float* c2_lb    = (const float*)d_in[14];
    const float* c2_rW    = (const float*)d_in[15];
    const float* d0_W     = (const float*)d_in[16];
    const float* d0_b     = (const float*)d_in[17];
    const float* d1_W     = (const float*)d_in[18];
    const float* d1_b     = (const float*)d_in[19];
    const float* d2_W     = (const float*)d_in[20];
    const float* d2_b     = (const float*)d_in[21];

    const int N = in_sizes[1];
    const int E = in_sizes[2] / 2;
    const int* src = ei;
    const int* dst = ei + E;

    // workspace (4-byte elems):
    //   R0 (256N): early = [rowptr(N+1)|cursor(N)|col(E)]; late = H0(256N)
    //   then A(96N) | B(96N) | C(96N)
    float* ws     = (float*)d_ws;
    float* H0     = ws;
    int*   rowptr = (int*)d_ws;
    int*   cursor = rowptr + (N + 1);
    int*   col    = cursor + N;
    float* A      = ws + (size_t)256 * N;
    float* B      = A + (size_t)96 * N;
    float* C      = B + (size_t)96 * N;

    const dim3 blk(NB);
    const int rt64 = (N + 63) / 64;
    const dim3 gE((E + NB - 1) / NB);
    const dim3 gGather(((size_t)N * 24 + NB - 1) / NB);

    // ---- CSR build ----
    hipMemsetAsync(cursor, 0, (size_t)N * sizeof(int), stream);
    count_int_kernel<<<gE, blk, 0, stream>>>(dst, cursor, E);
    scan_kernel<<<dim3(1), dim3(1024), 0, stream>>>(cursor, rowptr, cursor, N);
    fill_csr_kernel<<<gE, blk, 0, stream>>>(src, dst, cursor, col, E);

    // ---- embed + lin -> A (embedding fused; K=80 -> BK=16, QX=4) ----
    gemm4<80, 96, 64, 96, 4, 6, 16, false, false, true, false>
        <<<dim3(rt64), blk, 0, stream>>>(
        nullptr, nullptr, lin_W, nullptr, lin_b,
        x_layout, x_role, lemb, remb, nullptr, nullptr, A, N);

    // ---- layer 0: A -> C ----
    gather_mean_kernel<<<gGather, blk, 0, stream>>>(A, rowptr, col, B, N);
    gemm4<96, 96, 64, 96, 4, 6, 32, true, true, false, false>
        <<<dim3(rt64), blk, 0, stream>>>(
        A, B, c0_rW, c0_lW, c0_lb, nullptr, nullptr, nullptr, nullptr,
        nullptr, nullptr, C, N);

    // ---- layer 1: C -> A ----
    gather_mean_kernel<<<gGather, blk, 0, stream>>>(C, rowptr, col, B, N);
    gemm4<96, 96, 64, 96, 4, 6, 32, true, true, false, false>
        <<<dim3(rt64), blk, 0, stream>>>(
        C, B, c1_rW, c1_lW, c1_lb, nullptr, nullptr, nullptr, nullptr,
        nullptr, nullptr, A, N);

    // ---- layer 2: A -> C ----
    gather_mean_kernel<<<gGather, blk, 0, stream>>>(A, rowptr, col, B, N);
    gemm4<96, 96, 64, 96, 4, 6, 32, true, true, false, false>
        <<<dim3(rt64), blk, 0, stream>>>(
        A, B, c2_rW, c2_lW, c2_lb, nullptr, nullptr, nullptr, nullptr,
        nullptr, nullptr, C, N);

    // ---- head: d0 (C -> H0), then d1+d2 fused (H0 -> out) ----
    gemm4<96, 256, 64, 128, 4, 8, 32, true, false, false, false>
        <<<dim3(rt64 * 2), blk, 0, stream>>>(
        C, nullptr, d0_W, nullptr, d0_b, nullptr, nullptr, nullptr, nullptr,
        nullptr, nullptr, H0, N);

    hipMemsetAsync(d_out, 0, (size_t)N * sizeof(float), stream);
    gemm4<256, 256, 64, 128, 4, 8, 32, true, false, false, true>
        <<<dim3(rt64 * 2), blk, 0, stream>>>(
        H0, nullptr, d1_W, nullptr, d1_b, nullptr, nullptr, nullptr, nullptr,
        d2_W, d2_b, (float*)d_out, N);
}

// Round 9
// 968.347 us; speedup vs baseline: 2.3190x; 1.0463x over previous
//
#include <hip/hip_runtime.h>
#include <cstddef>

// ---------------------------------------------------------------------------
// embed+concat -> Linear(80->96) -> 3x SAGEConv(96, mean) -> MLP(96->256->256->1)
// fp32. N = in_sizes[1], E = in_sizes[2]/2.
// Round 9: row-major float4-slot LDS with ODD row stride (QX+1 slots): write
// 2-way (free), reads broadcast/2-way (free), affine addressing (no XOR, no
// VGPR blowup). BM=64, TM=4 micro-tiles. Fusions unchanged.
// ---------------------------------------------------------------------------

#define NB 256

// ---- CSR: count in-degree --------------------------------------------------
__global__ __launch_bounds__(NB) void count_int_kernel(const int* __restrict__ dst,
                                                       int* __restrict__ cnt, int E) {
    int e = blockIdx.x * NB + threadIdx.x;
    if (e < E) atomicAdd(&cnt[dst[e]], 1);
}

// ---- CSR: single-block exclusive scan --------------------------------------
__global__ __launch_bounds__(1024) void scan_kernel(const int* __restrict__ cnt,
                                                    int* __restrict__ rowptr,
                                                    int* __restrict__ cursor, int n) {
    __shared__ int buf[1024];
    __shared__ int carry;
    const int tid = threadIdx.x;
    if (tid == 0) carry = 0;
    __syncthreads();
    const int CH = 1024 * 8;
    for (int base = 0; base < n; base += CH) {
        int loc[8];
        int s = 0;
        #pragma unroll
        for (int q = 0; q < 8; ++q) {
            int i = base + tid * 8 + q;
            int v = (i < n) ? cnt[i] : 0;
            loc[q] = s;
            s += v;
        }
        buf[tid] = s;
        __syncthreads();
        for (int off = 1; off < 1024; off <<= 1) {
            int t = (tid >= off) ? buf[tid - off] : 0;
            __syncthreads();
            buf[tid] += t;
            __syncthreads();
        }
        int tpref = carry + buf[tid] - s;
        #pragma unroll
        for (int q = 0; q < 8; ++q) {
            int i = base + tid * 8 + q;
            if (i < n) {
                int v = tpref + loc[q];
                rowptr[i] = v;
                cursor[i] = v;
            }
        }
        int chunk = buf[1023];
        __syncthreads();
        if (tid == 0) carry += chunk;
        __syncthreads();
    }
    if (tid == 0) rowptr[n] = carry;
}

// ---- CSR: fill column (src) list -------------------------------------------
__global__ __launch_bounds__(NB) void fill_csr_kernel(const int* __restrict__ src,
                                                      const int* __restrict__ dst,
                                                      int* __restrict__ cursor,
                                                      int* __restrict__ col, int E) {
    int e = blockIdx.x * NB + threadIdx.x;
    if (e >= E) return;
    int p = atomicAdd(&cursor[dst[e]], 1);
    col[p] = src[e];
}

// ---- gather-mean: G[n] = mean_{j in col[rowptr[n]:rowptr[n+1]]} X[j] -------
__global__ __launch_bounds__(NB) void gather_mean_kernel(
    const float* __restrict__ X, const int* __restrict__ rowptr,
    const int* __restrict__ col, float* __restrict__ G, int N) {
    int idx = blockIdx.x * NB + threadIdx.x;
    int node = idx / 24;
    if (node >= N) return;
    int c = idx - node * 24;
    const int s = rowptr[node], pe = rowptr[node + 1];
    float4 acc = {0.f, 0.f, 0.f, 0.f};
    int p = s;
    for (; p + 3 < pe; p += 4) {
        int j0 = col[p], j1 = col[p + 1], j2 = col[p + 2], j3 = col[p + 3];
        float4 v0 = *reinterpret_cast<const float4*>(&X[(size_t)j0 * 96 + 4 * c]);
        float4 v1 = *reinterpret_cast<const float4*>(&X[(size_t)j1 * 96 + 4 * c]);
        float4 v2 = *reinterpret_cast<const float4*>(&X[(size_t)j2 * 96 + 4 * c]);
        float4 v3 = *reinterpret_cast<const float4*>(&X[(size_t)j3 * 96 + 4 * c]);
        acc.x += (v0.x + v1.x) + (v2.x + v3.x);
        acc.y += (v0.y + v1.y) + (v2.y + v3.y);
        acc.z += (v0.z + v1.z) + (v2.z + v3.z);
        acc.w += (v0.w + v1.w) + (v2.w + v3.w);
    }
    for (; p < pe; ++p) {
        int j = col[p];
        float4 v = *reinterpret_cast<const float4*>(&X[(size_t)j * 96 + 4 * c]);
        acc.x += v.x; acc.y += v.y; acc.z += v.z; acc.w += v.w;
    }
    int deg = pe - s;
    float inv = (deg > 0) ? 1.f / (float)deg : 0.f;
    acc.x *= inv; acc.y *= inv; acc.z *= inv; acc.w *= inv;
    *reinterpret_cast<float4*>(&G[(size_t)node * 96 + 4 * c]) = acc;
}

// ---- register-tiled GEMM, row-major float4-slot LDS, odd stride ------------
// Xs[m*(QX+1)+q] = float4 {row m, k's 4q..4q+3}. Row stride QX+1 slots (odd)
// -> bank-group (m+q)%8: staging ds_write_b128 2-way (free), a-reads 16-lane
// broadcast, b-reads 2-way + 4-lane broadcast (free). Affine addressing.
// Thread (tx,ty) of 16x16 owns rows ty+16*i, cols tx+16*j.
// EMB: X-load gathers embeddings. FDOT: out[r] += relu(row).d2w (atomicAdd).
// Grid 1D, col-tile fastest.
template <int K, int OUT, int BM, int BN, int TM, int TN, int BK,
          bool RELU, bool SAGE, bool EMB, bool FDOT>
__global__ __launch_bounds__(NB) void gemm5(
    const float* __restrict__ X, const float* __restrict__ G,
    const float* __restrict__ Wx, const float* __restrict__ Wg,
    const float* __restrict__ bias,
    const int* __restrict__ xl, const int* __restrict__ xr,
    const float* __restrict__ lemb, const float* __restrict__ remb,
    const float* __restrict__ d2w, const float* __restrict__ d2b,
    float* __restrict__ Y, int nrows) {
    constexpr int QX = BK / 4;       // k-chunks per BK step
    constexpr int ST = QX + 1;       // row stride in float4 slots (odd)
    constexpr int CT = OUT / BN;     // col tiles
    constexpr int KT = SAGE ? 2 * K : K;
    __shared__ float4 Xs[BM * ST];
    __shared__ float4 Ws[BN * ST];

    const int t = threadIdx.x;
    const int tx = t & 15, ty = t >> 4;
    const int bid = blockIdx.x;
    const int rowBase = (bid / CT) * BM;
    const int colTile = bid % CT;
    const int colBase = colTile * BN;

    float acc[TM][TN];
#pragma unroll
    for (int i = 0; i < TM; ++i)
#pragma unroll
        for (int j = 0; j < TN; ++j) acc[i][j] = 0.f;

    for (int k0 = 0; k0 < KT; k0 += BK) {
        const bool isG = SAGE && (k0 >= K);
        const float* __restrict__ Xp = isG ? G : X;
        const float* __restrict__ Wp = isG ? Wg : Wx;
        const int kl = isG ? (k0 - K) : k0;

        // ---- stage X tile: q fast across lanes (coalesced global), b128 write
        for (int v = t; v < BM * QX; v += NB) {
            int q = v % QX, m = v / QX;
            int r = rowBase + m;
            float4 f = {0.f, 0.f, 0.f, 0.f};
            if (r < nrows) {
                if (EMB) {
                    int kk = kl + 4 * q;
                    if (kk < 64) {
                        int l = kk >> 4, c = kk & 15;
                        f = *reinterpret_cast<const float4*>(
                            &lemb[(size_t)xl[r * 4 + l] * 16 + c]);
                    } else {
                        f = *reinterpret_cast<const float4*>(
                            &remb[(size_t)xr[r] * 16 + (kk - 64)]);
                    }
                } else {
                    f = *reinterpret_cast<const float4*>(&Xp[(size_t)r * K + kl + 4 * q]);
                }
            }
            Xs[m * ST + q] = f;
        }
        // ---- stage W tile
        for (int v = t; v < BN * QX; v += NB) {
            int q = v % QX, n = v / QX;
            float4 f = *reinterpret_cast<const float4*>(
                &Wp[(size_t)(colBase + n) * K + kl + 4 * q]);
            Ws[n * ST + q] = f;
        }
        __syncthreads();

#pragma unroll
        for (int q = 0; q < QX; ++q) {
            float4 a4[TM], b4[TN];
#pragma unroll
            for (int i = 0; i < TM; ++i) a4[i] = Xs[(ty + 16 * i) * ST + q];
#pragma unroll
            for (int j = 0; j < TN; ++j) b4[j] = Ws[(tx + 16 * j) * ST + q];
#pragma unroll
            for (int i = 0; i < TM; ++i)
#pragma unroll
                for (int j = 0; j < TN; ++j) {
                    acc[i][j] += a4[i].x * b4[j].x + a4[i].y * b4[j].y +
                                 a4[i].z * b4[j].z + a4[i].w * b4[j].w;
                }
        }
        __syncthreads();
    }

    if (!FDOT) {
#pragma unroll
        for (int i = 0; i < TM; ++i) {
            int r = rowBase + ty + 16 * i;
            if (r >= nrows) continue;
#pragma unroll
            for (int j = 0; j < TN; ++j) {
                int c = colBase + tx + 16 * j;
                float v = acc[i][j] + bias[c];
                if (RELU) v = fmaxf(v, 0.f);
                Y[(size_t)r * OUT + c] = v;
            }
        }
    } else {
#pragma unroll
        for (int i = 0; i < TM; ++i) {
            int r = rowBase + ty + 16 * i;
            float p = 0.f;
#pragma unroll
            for (int j = 0; j < TN; ++j) {
                int c = colBase + tx + 16 * j;
                float v = fmaxf(acc[i][j] + bias[c], 0.f);
                p += v * d2w[c];
            }
#pragma unroll
            for (int off = 1; off < 16; off <<= 1) p += __shfl_xor(p, off);
            if (tx == 0 && r < nrows)
                atomicAdd(&Y[r], p + (colTile == 0 ? d2b[0] : 0.f));
        }
    }
}

// ---------------------------------------------------------------------------
extern "C" void kernel_launch(void* const* d_in, const int* in_sizes, int n_in,
                              void* d_out, int out_size, void* d_ws, size_t ws_size,
                              hipStream_t stream) {
    const int*   x_layout = (const int*)d_in[0];
    const int*   x_role   = (const int*)d_in[1];
    const int*   ei       = (const int*)d_in[2];
    const float* lemb     = (const float*)d_in[3];
    const float* remb     = (const float*)d_in[4];
    const float* lin_W    = (const float*)d_in[5];
    const float* lin_b    = (const float*)d_in[6];
    const float* c0_lW    = (const float*)d_in[7];
    const float* c0_lb    = (const float*)d_in[8];
    const float* c0_rW    = (const float*)d_in[9];
    const float* c1_lW    = (const float*)d_in[10];
    const float* c1_lb    = (const float*)d_in[11];
    const float* c1_rW    = (const float*)d_in[12];
    const float* c2_lW    = (const float*)d_in[13];
    const float* c2_lb    = (const float*)d_in[14];
    const float* c2_rW    = (const float*)d_in[15];
    const float* d0_W     = (const float*)d_in[16];
    const float* d0_b     = (const float*)d_in[17];
    const float* d1_W     = (const float*)d_in[18];
    const float* d1_b     = (const float*)d_in[19];
    const float* d2_W     = (const float*)d_in[20];
    const float* d2_b     = (const float*)d_in[21];

    const int N = in_sizes[1];
    const int E = in_sizes[2] / 2;
    const int* src = ei;
    const int* dst = ei + E;

    // workspace (4-byte elems):
    //   R0 (256N): early = [rowptr(N+1)|cursor(N)|col(E)]; late = H0(256N)
    //   then A(96N) | B(96N) | C(96N)
    float* ws     = (float*)d_ws;
    float* H0     = ws;
    int*   rowptr = (int*)d_ws;
    int*   cursor = rowptr + (N + 1);
    int*   col    = cursor + N;
    float* A      = ws + (size_t)256 * N;
    float* B      = A + (size_t)96 * N;
    float* C      = B + (size_t)96 * N;

    const dim3 blk(NB);
    const int rt64 = (N + 63) / 64;
    const dim3 gE((E + NB - 1) / NB);
    const dim3 gGather(((size_t)N * 24 + NB - 1) / NB);

    // ---- CSR build ----
    hipMemsetAsync(cursor, 0, (size_t)N * sizeof(int), stream);
    count_int_kernel<<<gE, blk, 0, stream>>>(dst, cursor, E);
    scan_kernel<<<dim3(1), dim3(1024), 0, stream>>>(cursor, rowptr, cursor, N);
    fill_csr_kernel<<<gE, blk, 0, stream>>>(src, dst, cursor, col, E);

    // ---- embed + lin -> A (embedding fused; K=80 -> BK=16, QX=4) ----
    gemm5<80, 96, 64, 96, 4, 6, 16, false, false, true, false>
        <<<dim3(rt64), blk, 0, stream>>>(
        nullptr, nullptr, lin_W, nullptr, lin_b,
        x_layout, x_role, lemb, remb, nullptr, nullptr, A, N);

    // ---- layer 0: A -> C ----
    gather_mean_kernel<<<gGather, blk, 0, stream>>>(A, rowptr, col, B, N);
    gemm5<96, 96, 64, 96, 4, 6, 32, true, true, false, false>
        <<<dim3(rt64), blk, 0, stream>>>(
        A, B, c0_rW, c0_lW, c0_lb, nullptr, nullptr, nullptr, nullptr,
        nullptr, nullptr, C, N);

    // ---- layer 1: C -> A ----
    gather_mean_kernel<<<gGather, blk, 0, stream>>>(C, rowptr, col, B, N);
    gemm5<96, 96, 64, 96, 4, 6, 32, true, true, false, false>
        <<<dim3(rt64), blk, 0, stream>>>(
        C, B, c1_rW, c1_lW, c1_lb, nullptr, nullptr, nullptr, nullptr,
        nullptr, nullptr, A, N);

    // ---- layer 2: A -> C ----
    gather_mean_kernel<<<gGather, blk, 0, stream>>>(A, rowptr, col, B, N);
    gemm5<96, 96, 64, 96, 4, 6, 32, true, true, false, false>
        <<<dim3(rt64), blk, 0, stream>>>(
        A, B, c2_rW, c2_lW, c2_lb, nullptr, nullptr, nullptr, nullptr,
        nullptr, nullptr, C, N);

    // ---- head: d0 (C -> H0), then d1+d2 fused (H0 -> out) ----
    gemm5<96, 256, 64, 128, 4, 8, 32, true, false, false, false>
        <<<dim3(rt64 * 2), blk, 0, stream>>>(
        C, nullptr, d0_W, nullptr, d0_b, nullptr, nullptr, nullptr, nullptr,
        nullptr, nullptr, H0, N);

    hipMemsetAsync(d_out, 0, (size_t)N * sizeof(float), stream);
    gemm5<256, 256, 64, 128, 4, 8, 32, true, false, false, true>
        <<<dim3(rt64 * 2), blk, 0, stream>>>(
        H0, nullptr, d1_W, nullptr, d1_b, nullptr, nullptr, nullptr, nullptr,
        d2_W, d2_b, (float*)d_out, N);
}

// Round 10
// 673.502 us; speedup vs baseline: 3.3341x; 1.4378x over previous
//
#include <hip/hip_runtime.h>
#include <cstddef>

// ---------------------------------------------------------------------------
// embed+concat -> Linear(80->96) -> 3x SAGEConv(96, mean) -> MLP(96->256->256->1)
// fp32. N = in_sizes[1], E = in_sizes[2]/2.
// Round 10: r6 champion structure restored; pad +4 -> +2 so staging-write
// bank = (8q+2u+m) mod 32 = exact 2-way (free). lin GEMM moved to BM=64/TM=4
// (kills its 4-way a-reads). Everything else identical to round 6.
// ---------------------------------------------------------------------------

#define NB 256

// ---- CSR: count in-degree --------------------------------------------------
__global__ __launch_bounds__(NB) void count_int_kernel(const int* __restrict__ dst,
                                                       int* __restrict__ cnt, int E) {
    int e = blockIdx.x * NB + threadIdx.x;
    if (e < E) atomicAdd(&cnt[dst[e]], 1);
}

// ---- CSR: single-block exclusive scan --------------------------------------
__global__ __launch_bounds__(1024) void scan_kernel(const int* __restrict__ cnt,
                                                    int* __restrict__ rowptr,
                                                    int* __restrict__ cursor, int n) {
    __shared__ int buf[1024];
    __shared__ int carry;
    const int tid = threadIdx.x;
    if (tid == 0) carry = 0;
    __syncthreads();
    const int CH = 1024 * 8;
    for (int base = 0; base < n; base += CH) {
        int loc[8];
        int s = 0;
        #pragma unroll
        for (int q = 0; q < 8; ++q) {
            int i = base + tid * 8 + q;
            int v = (i < n) ? cnt[i] : 0;
            loc[q] = s;
            s += v;
        }
        buf[tid] = s;
        __syncthreads();
        for (int off = 1; off < 1024; off <<= 1) {
            int t = (tid >= off) ? buf[tid - off] : 0;
            __syncthreads();
            buf[tid] += t;
            __syncthreads();
        }
        int tpref = carry + buf[tid] - s;
        #pragma unroll
        for (int q = 0; q < 8; ++q) {
            int i = base + tid * 8 + q;
            if (i < n) {
                int v = tpref + loc[q];
                rowptr[i] = v;
                cursor[i] = v;
            }
        }
        int chunk = buf[1023];
        __syncthreads();
        if (tid == 0) carry += chunk;
        __syncthreads();
    }
    if (tid == 0) rowptr[n] = carry;
}

// ---- CSR: fill column (src) list -------------------------------------------
__global__ __launch_bounds__(NB) void fill_csr_kernel(const int* __restrict__ src,
                                                      const int* __restrict__ dst,
                                                      int* __restrict__ cursor,
                                                      int* __restrict__ col, int E) {
    int e = blockIdx.x * NB + threadIdx.x;
    if (e >= E) return;
    int p = atomicAdd(&cursor[dst[e]], 1);
    col[p] = src[e];
}

// ---- gather-mean: G[n] = mean_{j in col[rowptr[n]:rowptr[n+1]]} X[j] -------
__global__ __launch_bounds__(NB) void gather_mean_kernel(
    const float* __restrict__ X, const int* __restrict__ rowptr,
    const int* __restrict__ col, float* __restrict__ G, int N) {
    int idx = blockIdx.x * NB + threadIdx.x;
    int node = idx / 24;
    if (node >= N) return;
    int c = idx - node * 24;
    const int s = rowptr[node], pe = rowptr[node + 1];
    float4 acc = {0.f, 0.f, 0.f, 0.f};
    int p = s;
    for (; p + 3 < pe; p += 4) {
        int j0 = col[p], j1 = col[p + 1], j2 = col[p + 2], j3 = col[p + 3];
        float4 v0 = *reinterpret_cast<const float4*>(&X[(size_t)j0 * 96 + 4 * c]);
        float4 v1 = *reinterpret_cast<const float4*>(&X[(size_t)j1 * 96 + 4 * c]);
        float4 v2 = *reinterpret_cast<const float4*>(&X[(size_t)j2 * 96 + 4 * c]);
        float4 v3 = *reinterpret_cast<const float4*>(&X[(size_t)j3 * 96 + 4 * c]);
        acc.x += (v0.x + v1.x) + (v2.x + v3.x);
        acc.y += (v0.y + v1.y) + (v2.y + v3.y);
        acc.z += (v0.z + v1.z) + (v2.z + v3.z);
        acc.w += (v0.w + v1.w) + (v2.w + v3.w);
    }
    for (; p < pe; ++p) {
        int j = col[p];
        float4 v = *reinterpret_cast<const float4*>(&X[(size_t)j * 96 + 4 * c]);
        acc.x += v.x; acc.y += v.y; acc.z += v.z; acc.w += v.w;
    }
    int deg = pe - s;
    float inv = (deg > 0) ? 1.f / (float)deg : 0.f;
    acc.x *= inv; acc.y *= inv; acc.z *= inv; acc.w *= inv;
    *reinterpret_cast<float4*>(&G[(size_t)node * 96 + 4 * c]) = acc;
}

// ---- register-tiled GEMM (r6 structure, +2 pad) ----------------------------
// Y = act(X @ Wx^T [+ G @ Wg^T] + bias); EMB: X-load gathers embeddings;
// FDOT: out[r] += relu(row).d2w (atomicAdd). Grid 1D, col-tile fastest.
// 256 thr as 16x16. Thread (tx,ty): rows ty*TM+i (contiguous -> b128 reads),
// cols tx*G4+(j%G4)+SPAN*(j/G4) (contiguous groups -> b128/b64 reads).
// Pad +2: staging-write bank = (8q+2u+m)%32 -> exact 2-way (free).
template <int K, int OUT, int BM, int BN, int TM, int TN, int BK,
          bool RELU, bool SAGE, bool EMB, bool FDOT>
__global__ __launch_bounds__(NB) void gemm2(
    const float* __restrict__ X, const float* __restrict__ G,
    const float* __restrict__ Wx, const float* __restrict__ Wg,
    const float* __restrict__ bias,
    const int* __restrict__ xl, const int* __restrict__ xr,
    const float* __restrict__ lemb, const float* __restrict__ remb,
    const float* __restrict__ d2w, const float* __restrict__ d2b,
    float* __restrict__ Y, int nrows) {
    constexpr int G4   = (TN % 4 == 0) ? 4 : 2;   // col group size
    constexpr int SPAN = 16 * G4;                 // group stride
    constexpr int QX   = BK / 4;
    constexpr int CT   = OUT / BN;
    constexpr int KT   = SAGE ? 2 * K : K;
    __shared__ float Xs[BK][BM + 2];
    __shared__ float Ws[BK][BN + 2];

    const int t = threadIdx.x;
    const int tx = t & 15, ty = t >> 4;
    const int bid = blockIdx.x;
    const int rowBase = (bid / CT) * BM;
    const int colTile = bid % CT;
    const int colBase = colTile * BN;

    float acc[TM][TN];
#pragma unroll
    for (int i = 0; i < TM; ++i)
#pragma unroll
        for (int j = 0; j < TN; ++j) acc[i][j] = 0.f;

    for (int k0 = 0; k0 < KT; k0 += BK) {
        const bool isG = SAGE && (k0 >= K);
        const float* __restrict__ Xp = isG ? G : X;
        const float* __restrict__ Wp = isG ? Wg : Wx;
        const int kl = isG ? (k0 - K) : k0;

        // X tile -> Xs[k][m] (transposed; q fast across lanes = coalesced)
        for (int v = t; v < BM * QX; v += NB) {
            int m = v / QX, q = v % QX;
            int r = rowBase + m;
            float4 f = {0.f, 0.f, 0.f, 0.f};
            if (r < nrows) {
                if (EMB) {
                    int kk = kl + 4 * q;
                    if (kk < 64) {
                        int l = kk >> 4, c = kk & 15;
                        f = *reinterpret_cast<const float4*>(
                            &lemb[(size_t)xl[r * 4 + l] * 16 + c]);
                    } else {
                        f = *reinterpret_cast<const float4*>(
                            &remb[(size_t)xr[r] * 16 + (kk - 64)]);
                    }
                } else {
                    f = *reinterpret_cast<const float4*>(&Xp[(size_t)r * K + kl + 4 * q]);
                }
            }
            Xs[4 * q + 0][m] = f.x;
            Xs[4 * q + 1][m] = f.y;
            Xs[4 * q + 2][m] = f.z;
            Xs[4 * q + 3][m] = f.w;
        }
        // W tile -> Ws[k][n]
        for (int v = t; v < BN * QX; v += NB) {
            int n = v / QX, q = v % QX;
            float4 f = *reinterpret_cast<const float4*>(
                &Wp[(size_t)(colBase + n) * K + kl + 4 * q]);
            Ws[4 * q + 0][n] = f.x;
            Ws[4 * q + 1][n] = f.y;
            Ws[4 * q + 2][n] = f.z;
            Ws[4 * q + 3][n] = f.w;
        }
        __syncthreads();

#pragma unroll
        for (int k = 0; k < BK; ++k) {
            float a[TM], b[TN];
#pragma unroll
            for (int i = 0; i < TM; ++i) a[i] = Xs[k][ty * TM + i];
#pragma unroll
            for (int j = 0; j < TN; ++j)
                b[j] = Ws[k][tx * G4 + (j % G4) + SPAN * (j / G4)];
#pragma unroll
            for (int i = 0; i < TM; ++i)
#pragma unroll
                for (int j = 0; j < TN; ++j) acc[i][j] += a[i] * b[j];
        }
        __syncthreads();
    }

    if (!FDOT) {
#pragma unroll
        for (int i = 0; i < TM; ++i) {
            int r = rowBase + ty * TM + i;
            if (r >= nrows) continue;
#pragma unroll
            for (int g = 0; g < TN / G4; ++g) {
                int cb = colBase + tx * G4 + SPAN * g;
                float vv[G4];
#pragma unroll
                for (int u = 0; u < G4; ++u) {
                    float v = acc[i][g * G4 + u] + bias[cb + u];
                    if (RELU) v = fmaxf(v, 0.f);
                    vv[u] = v;
                }
                if (G4 == 4) {
                    float4 o = {vv[0], vv[1], vv[2], vv[3]};
                    *reinterpret_cast<float4*>(&Y[(size_t)r * OUT + cb]) = o;
                } else {
                    float2 o = {vv[0], vv[1]};
                    *reinterpret_cast<float2*>(&Y[(size_t)r * OUT + cb]) = o;
                }
            }
        }
    } else {
#pragma unroll
        for (int i = 0; i < TM; ++i) {
            int r = rowBase + ty * TM + i;
            float p = 0.f;
#pragma unroll
            for (int j = 0; j < TN; ++j) {
                int c = colBase + tx * G4 + (j % G4) + SPAN * (j / G4);
                float v = fmaxf(acc[i][j] + bias[c], 0.f);
                p += v * d2w[c];
            }
#pragma unroll
            for (int off = 1; off < 16; off <<= 1) p += __shfl_xor(p, off);
            if (tx == 0 && r < nrows)
                atomicAdd(&Y[r], p + (colTile == 0 ? d2b[0] : 0.f));
        }
    }
}

// ---------------------------------------------------------------------------
extern "C" void kernel_launch(void* const* d_in, const int* in_sizes, int n_in,
                              void* d_out, int out_size, void* d_ws, size_t ws_size,
                              hipStream_t stream) {
    const int*   x_layout = (const int*)d_in[0];
    const int*   x_role   = (const int*)d_in[1];
    const int*   ei       = (const int*)d_in[2];
    const float* lemb     = (const float*)d_in[3];
    const float* remb     = (const float*)d_in[4];
    const float* lin_W    = (const float*)d_in[5];
    const float* lin_b    = (const float*)d_in[6];
    const float* c0_lW    = (const float*)d_in[7];
    const float* c0_lb    = (const float*)d_in[8];
    const float* c0_rW    = (const float*)d_in[9];
    const float* c1_lW    = (const float*)d_in[10];
    const float* c1_lb    = (const float*)d_in[11];
    const float* c1_rW    = (const float*)d_in[12];
    const float* c2_lW    = (const float*)d_in[13];
    const float* c2_lb    = (const float*)d_in[14];
    const float* c2_rW    = (const float*)d_in[15];
    const float* d0_W     = (const float*)d_in[16];
    const float* d0_b     = (const float*)d_in[17];
    const float* d1_W     = (const float*)d_in[18];
    const float* d1_b     = (const float*)d_in[19];
    const float* d2_W     = (const float*)d_in[20];
    const float* d2_b     = (const float*)d_in[21];

    const int N = in_sizes[1];
    const int E = in_sizes[2] / 2;
    const int* src = ei;
    const int* dst = ei + E;

    // workspace (4-byte elems):
    //   R0 (256N): early = [rowptr(N+1)|cursor(N)|col(E)]; late = H0(256N)
    //   then A(96N) | B(96N) | C(96N)
    float* ws     = (float*)d_ws;
    float* H0     = ws;
    int*   rowptr = (int*)d_ws;
    int*   cursor = rowptr + (N + 1);
    int*   col    = cursor + N;
    float* A      = ws + (size_t)256 * N;
    float* B      = A + (size_t)96 * N;
    float* C      = B + (size_t)96 * N;

    const dim3 blk(NB);
    const int rt64 = (N + 63) / 64;
    const dim3 gE((E + NB - 1) / NB);
    const dim3 gGather(((size_t)N * 24 + NB - 1) / NB);

    // ---- CSR build ----
    hipMemsetAsync(cursor, 0, (size_t)N * sizeof(int), stream);
    count_int_kernel<<<gE, blk, 0, stream>>>(dst, cursor, E);
    scan_kernel<<<dim3(1), dim3(1024), 0, stream>>>(cursor, rowptr, cursor, N);
    fill_csr_kernel<<<gE, blk, 0, stream>>>(src, dst, cursor, col, E);

    // ---- embed + lin -> A (embedding fused; K=80 -> BK=16) ----
    gemm2<80, 96, 64, 96, 4, 6, 16, false, false, true, false>
        <<<dim3(rt64), blk, 0, stream>>>(
        nullptr, nullptr, lin_W, nullptr, lin_b,
        x_layout, x_role, lemb, remb, nullptr, nullptr, A, N);

    // ---- layer 0: A -> C ----
    gather_mean_kernel<<<gGather, blk, 0, stream>>>(A, rowptr, col, B, N);
    gemm2<96, 96, 64, 96, 4, 6, 32, true, true, false, false>
        <<<dim3(rt64), blk, 0, stream>>>(
        A, B, c0_rW, c0_lW, c0_lb, nullptr, nullptr, nullptr, nullptr,
        nullptr, nullptr, C, N);

    // ---- layer 1: C -> A ----
    gather_mean_kernel<<<gGather, blk, 0, stream>>>(C, rowptr, col, B, N);
    gemm2<96, 96, 64, 96, 4, 6, 32, true, true, false, false>
        <<<dim3(rt64), blk, 0, stream>>>(
        C, B, c1_rW, c1_lW, c1_lb, nullptr, nullptr, nullptr, nullptr,
        nullptr, nullptr, A, N);

    // ---- layer 2: A -> C ----
    gather_mean_kernel<<<gGather, blk, 0, stream>>>(A, rowptr, col, B, N);
    gemm2<96, 96, 64, 96, 4, 6, 32, true, true, false, false>
        <<<dim3(rt64), blk, 0, stream>>>(
        A, B, c2_rW, c2_lW, c2_lb, nullptr, nullptr, nullptr, nullptr,
        nullptr, nullptr, C, N);

    // ---- head: d0 (C -> H0), then d1+d2 fused (H0 -> out) ----
    gemm2<96, 256, 64, 128, 4, 8, 32, true, false, false, false>
        <<<dim3(rt64 * 2), blk, 0, stream>>>(
        C, nullptr, d0_W, nullptr, d0_b, nullptr, nullptr, nullptr, nullptr,
        nullptr, nullptr, H0, N);

    hipMemsetAsync(d_out, 0, (size_t)N * sizeof(float), stream);
    gemm2<256, 256, 64, 128, 4, 8, 32, true, false, false, true>
        <<<dim3(rt64 * 2), blk, 0, stream>>>(
        H0, nullptr, d1_W, nullptr, d1_b, nullptr, nullptr, nullptr, nullptr,
        d2_W, d2_b, (float*)d_out, N);
}

// Round 11
// 565.672 us; speedup vs baseline: 3.9697x; 1.1906x over previous
//
#include <hip/hip_runtime.h>
#include <cstddef>

// ---------------------------------------------------------------------------
// embed+concat -> Linear(80->96) -> 3x SAGEConv(96, mean) -> MLP(96->256->256->1)
// fp32 in/out. N = in_sizes[1], E = in_sizes[2]/2.
// Round 11: all dense layers on MFMA (v_mfma_f32_16x16x16f16) with fp16
// two-term split (hi+lo, 3 products) for fp32-grade accuracy. 4 waves/block
// (2x2), 16x16 tiles, f16 LDS staging. CSR + gather-mean unchanged (proven).
// ---------------------------------------------------------------------------

#define NB 256

using f16x4 = __attribute__((ext_vector_type(4))) _Float16;
using f32x4 = __attribute__((ext_vector_type(4))) float;

// ---- CSR: count in-degree --------------------------------------------------
__global__ __launch_bounds__(NB) void count_int_kernel(const int* __restrict__ dst,
                                                       int* __restrict__ cnt, int E) {
    int e = blockIdx.x * NB + threadIdx.x;
    if (e < E) atomicAdd(&cnt[dst[e]], 1);
}

// ---- CSR: single-block exclusive scan --------------------------------------
__global__ __launch_bounds__(1024) void scan_kernel(const int* __restrict__ cnt,
                                                    int* __restrict__ rowptr,
                                                    int* __restrict__ cursor, int n) {
    __shared__ int buf[1024];
    __shared__ int carry;
    const int tid = threadIdx.x;
    if (tid == 0) carry = 0;
    __syncthreads();
    const int CH = 1024 * 8;
    for (int base = 0; base < n; base += CH) {
        int loc[8];
        int s = 0;
        #pragma unroll
        for (int q = 0; q < 8; ++q) {
            int i = base + tid * 8 + q;
            int v = (i < n) ? cnt[i] : 0;
            loc[q] = s;
            s += v;
        }
        buf[tid] = s;
        __syncthreads();
        for (int off = 1; off < 1024; off <<= 1) {
            int t = (tid >= off) ? buf[tid - off] : 0;
            __syncthreads();
            buf[tid] += t;
            __syncthreads();
        }
        int tpref = carry + buf[tid] - s;
        #pragma unroll
        for (int q = 0; q < 8; ++q) {
            int i = base + tid * 8 + q;
            if (i < n) {
                int v = tpref + loc[q];
                rowptr[i] = v;
                cursor[i] = v;
            }
        }
        int chunk = buf[1023];
        __syncthreads();
        if (tid == 0) carry += chunk;
        __syncthreads();
    }
    if (tid == 0) rowptr[n] = carry;
}

// ---- CSR: fill column (src) list -------------------------------------------
__global__ __launch_bounds__(NB) void fill_csr_kernel(const int* __restrict__ src,
                                                      const int* __restrict__ dst,
                                                      int* __restrict__ cursor,
                                                      int* __restrict__ col, int E) {
    int e = blockIdx.x * NB + threadIdx.x;
    if (e >= E) return;
    int p = atomicAdd(&cursor[dst[e]], 1);
    col[p] = src[e];
}

// ---- gather-mean: G[n] = mean_{j in col[rowptr[n]:rowptr[n+1]]} X[j] -------
__global__ __launch_bounds__(NB) void gather_mean_kernel(
    const float* __restrict__ X, const int* __restrict__ rowptr,
    const int* __restrict__ col, float* __restrict__ G, int N) {
    int idx = blockIdx.x * NB + threadIdx.x;
    int node = idx / 24;
    if (node >= N) return;
    int c = idx - node * 24;
    const int s = rowptr[node], pe = rowptr[node + 1];
    float4 acc = {0.f, 0.f, 0.f, 0.f};
    int p = s;
    for (; p + 3 < pe; p += 4) {
        int j0 = col[p], j1 = col[p + 1], j2 = col[p + 2], j3 = col[p + 3];
        float4 v0 = *reinterpret_cast<const float4*>(&X[(size_t)j0 * 96 + 4 * c]);
        float4 v1 = *reinterpret_cast<const float4*>(&X[(size_t)j1 * 96 + 4 * c]);
        float4 v2 = *reinterpret_cast<const float4*>(&X[(size_t)j2 * 96 + 4 * c]);
        float4 v3 = *reinterpret_cast<const float4*>(&X[(size_t)j3 * 96 + 4 * c]);
        acc.x += (v0.x + v1.x) + (v2.x + v3.x);
        acc.y += (v0.y + v1.y) + (v2.y + v3.y);
        acc.z += (v0.z + v1.z) + (v2.z + v3.z);
        acc.w += (v0.w + v1.w) + (v2.w + v3.w);
    }
    for (; p < pe; ++p) {
        int j = col[p];
        float4 v = *reinterpret_cast<const float4*>(&X[(size_t)j * 96 + 4 * c]);
        acc.x += v.x; acc.y += v.y; acc.z += v.z; acc.w += v.w;
    }
    int deg = pe - s;
    float inv = (deg > 0) ? 1.f / (float)deg : 0.f;
    acc.x *= inv; acc.y *= inv; acc.z *= inv; acc.w *= inv;
    *reinterpret_cast<float4*>(&G[(size_t)node * 96 + 4 * c]) = acc;
}

// ---- fp32 -> (hi, lo) f16 split --------------------------------------------
__device__ inline void cvt_split(float4 f, f16x4& hi, f16x4& lo) {
    _Float16 h0 = (_Float16)f.x, h1 = (_Float16)f.y;
    _Float16 h2 = (_Float16)f.z, h3 = (_Float16)f.w;
    hi = (f16x4){h0, h1, h2, h3};
    lo = (f16x4){(_Float16)(f.x - (float)h0), (_Float16)(f.y - (float)h1),
                 (_Float16)(f.z - (float)h2), (_Float16)(f.w - (float)h3)};
}

// ---- MFMA GEMM: Y = act(X @ Wx^T [+ G @ Wg^T] + bias) ----------------------
// fp16-split: acc += Ahi*Bhi + Ahi*Blo + Alo*Bhi (lo*lo dropped, ~2^-22).
// v_mfma_f32_16x16x16f16 layouts (AMD-documented, CDNA1+):
//   A[m][k]: lane = m + 16*(k/4), elem j -> k = 4*(lane>>4)+j
//   B[k][n]: lane = n + 16*(k/4), elem j -> same k
//   D[m][n]: lane = n + 16*(m/4), elem j -> m = 4*(lane>>4)+j
// Block: 256 thr = 4 waves (2x2). Wave (wr,wc) owns rows wm+0..31 (2 tiles),
// cols wn + 0..16*TC-1 (TC tiles). BM=64, BN=32*TC... no: BN=2*TC*16.
// EMB: X-load gathers embeddings. FDOT: out[r] += relu(row).d2w (atomicAdd).
// Grid 1D, col-tile fastest.
template <int K, int OUT, int TC, int BK, bool RELU, bool SAGE, bool EMB, bool FDOT>
__global__ __launch_bounds__(NB) void gemm_mfma(
    const float* __restrict__ X, const float* __restrict__ G,
    const float* __restrict__ Wx, const float* __restrict__ Wg,
    const float* __restrict__ bias,
    const int* __restrict__ xl, const int* __restrict__ xr,
    const float* __restrict__ lemb, const float* __restrict__ remb,
    const float* __restrict__ d2w, const float* __restrict__ d2b,
    float* __restrict__ Y, int nrows) {
    constexpr int BM = 64;
    constexpr int BN = 2 * TC * 16;   // 2 wave-cols x TC tiles
    constexpr int CT = OUT / BN;
    constexpr int KT = SAGE ? 2 * K : K;
    constexpr int QX = BK / 4;
    constexpr int ST = BK + 4;        // f16 row stride (8B-aligned accesses)
    __shared__ alignas(16) _Float16 Xhi[BM][ST];
    __shared__ alignas(16) _Float16 Xlo[BM][ST];
    __shared__ alignas(16) _Float16 Whi[BN][ST];
    __shared__ alignas(16) _Float16 Wlo[BN][ST];

    const int t = threadIdx.x;
    const int lane = t & 63;
    const int wave = t >> 6;
    const int lm = lane & 15, lg = lane >> 4;
    const int wm = (wave >> 1) * 32;          // wave row offset
    const int wn = (wave & 1) * (TC * 16);    // wave col offset

    const int bid = blockIdx.x;
    const int rowBase = (bid / CT) * BM;
    const int colTile = bid % CT;
    const int colBase = colTile * BN;

    f32x4 acc[2][TC];
#pragma unroll
    for (int tr = 0; tr < 2; ++tr)
#pragma unroll
        for (int tc = 0; tc < TC; ++tc) acc[tr][tc] = (f32x4){0.f, 0.f, 0.f, 0.f};

    for (int k0 = 0; k0 < KT; k0 += BK) {
        const bool isG = SAGE && (k0 >= K);
        const float* __restrict__ Xp = isG ? G : X;
        const float* __restrict__ Wp = isG ? Wg : Wx;
        const int kl = isG ? (k0 - K) : k0;

        // ---- stage X tile (q fast across lanes = coalesced global reads)
        for (int v = t; v < BM * QX; v += NB) {
            int q = v % QX, m = v / QX;
            int r = rowBase + m;
            float4 f = {0.f, 0.f, 0.f, 0.f};
            if (r < nrows) {
                if (EMB) {
                    int kk = kl + 4 * q;
                    if (kk < 64) {
                        int l = kk >> 4, c = kk & 15;
                        f = *reinterpret_cast<const float4*>(
                            &lemb[(size_t)xl[r * 4 + l] * 16 + c]);
                    } else {
                        f = *reinterpret_cast<const float4*>(
                            &remb[(size_t)xr[r] * 16 + (kk - 64)]);
                    }
                } else {
                    f = *reinterpret_cast<const float4*>(&Xp[(size_t)r * K + kl + 4 * q]);
                }
            }
            f16x4 hi, lo;
            cvt_split(f, hi, lo);
            *reinterpret_cast<f16x4*>(&Xhi[m][4 * q]) = hi;
            *reinterpret_cast<f16x4*>(&Xlo[m][4 * q]) = lo;
        }
        // ---- stage W tile
        for (int v = t; v < BN * QX; v += NB) {
            int q = v % QX, n = v / QX;
            float4 f = *reinterpret_cast<const float4*>(
                &Wp[(size_t)(colBase + n) * K + kl + 4 * q]);
            f16x4 hi, lo;
            cvt_split(f, hi, lo);
            *reinterpret_cast<f16x4*>(&Whi[n][4 * q]) = hi;
            *reinterpret_cast<f16x4*>(&Wlo[n][4 * q]) = lo;
        }
        __syncthreads();

#pragma unroll
        for (int g = 0; g < BK / 16; ++g) {
            f16x4 ah[2], al[2], bh[TC], bl[TC];
#pragma unroll
            for (int tr = 0; tr < 2; ++tr) {
                ah[tr] = *reinterpret_cast<const f16x4*>(
                    &Xhi[wm + tr * 16 + lm][g * 16 + 4 * lg]);
                al[tr] = *reinterpret_cast<const f16x4*>(
                    &Xlo[wm + tr * 16 + lm][g * 16 + 4 * lg]);
            }
#pragma unroll
            for (int tc = 0; tc < TC; ++tc) {
                bh[tc] = *reinterpret_cast<const f16x4*>(
                    &Whi[wn + tc * 16 + lm][g * 16 + 4 * lg]);
                bl[tc] = *reinterpret_cast<const f16x4*>(
                    &Wlo[wn + tc * 16 + lm][g * 16 + 4 * lg]);
            }
#pragma unroll
            for (int tr = 0; tr < 2; ++tr)
#pragma unroll
                for (int tc = 0; tc < TC; ++tc) {
                    acc[tr][tc] = __builtin_amdgcn_mfma_f32_16x16x16f16(
                        ah[tr], bh[tc], acc[tr][tc], 0, 0, 0);
                    acc[tr][tc] = __builtin_amdgcn_mfma_f32_16x16x16f16(
                        ah[tr], bl[tc], acc[tr][tc], 0, 0, 0);
                    acc[tr][tc] = __builtin_amdgcn_mfma_f32_16x16x16f16(
                        al[tr], bh[tc], acc[tr][tc], 0, 0, 0);
                }
        }
        __syncthreads();
    }

    if (!FDOT) {
#pragma unroll
        for (int tr = 0; tr < 2; ++tr)
#pragma unroll
            for (int tc = 0; tc < TC; ++tc) {
                int c = colBase + wn + tc * 16 + lm;
#pragma unroll
                for (int j = 0; j < 4; ++j) {
                    int r = rowBase + wm + tr * 16 + 4 * lg + j;
                    if (r >= nrows) continue;
                    float v = acc[tr][tc][j] + bias[c];
                    if (RELU) v = fmaxf(v, 0.f);
                    Y[(size_t)r * OUT + c] = v;
                }
            }
    } else {
#pragma unroll
        for (int tr = 0; tr < 2; ++tr) {
            float p[4] = {0.f, 0.f, 0.f, 0.f};
#pragma unroll
            for (int tc = 0; tc < TC; ++tc) {
                int c = colBase + wn + tc * 16 + lm;
                float bv = bias[c];
                float dw = d2w[c];
#pragma unroll
                for (int j = 0; j < 4; ++j) {
                    float v = fmaxf(acc[tr][tc][j] + bv, 0.f);
                    p[j] += v * dw;
                }
            }
#pragma unroll
            for (int j = 0; j < 4; ++j) {
                float s = p[j];
#pragma unroll
                for (int off = 1; off < 16; off <<= 1) s += __shfl_xor(s, off);
                int r = rowBase + wm + tr * 16 + 4 * lg + j;
                if (lm == 0 && r < nrows) {
                    float extra = (colTile == 0 && wn == 0) ? d2b[0] : 0.f;
                    atomicAdd(&Y[r], s + extra);
                }
            }
        }
    }
}

// ---------------------------------------------------------------------------
extern "C" void kernel_launch(void* const* d_in, const int* in_sizes, int n_in,
                              void* d_out, int out_size, void* d_ws, size_t ws_size,
                              hipStream_t stream) {
    const int*   x_layout = (const int*)d_in[0];
    const int*   x_role   = (const int*)d_in[1];
    const int*   ei       = (const int*)d_in[2];
    const float* lemb     = (const float*)d_in[3];
    const float* remb     = (const float*)d_in[4];
    const float* lin_W    = (const float*)d_in[5];
    const float* lin_b    = (const float*)d_in[6];
    const float* c0_lW    = (const float*)d_in[7];
    const float* c0_lb    = (const float*)d_in[8];
    const float* c0_rW    = (const float*)d_in[9];
    const float* c1_lW    = (const float*)d_in[10];
    const float* c1_lb    = (const float*)d_in[11];
    const float* c1_rW    = (const float*)d_in[12];
    const float* c2_lW    = (const float*)d_in[13];
    const float* c2_lb    = (const float*)d_in[14];
    const float* c2_rW    = (const float*)d_in[15];
    const float* d0_W     = (const float*)d_in[16];
    const float* d0_b     = (const float*)d_in[17];
    const float* d1_W     = (const float*)d_in[18];
    const float* d1_b     = (const float*)d_in[19];
    const float* d2_W     = (const float*)d_in[20];
    const float* d2_b     = (const float*)d_in[21];

    const int N = in_sizes[1];
    const int E = in_sizes[2] / 2;
    const int* src = ei;
    const int* dst = ei + E;

    // workspace (4-byte elems):
    //   R0 (256N): early = [rowptr(N+1)|cursor(N)|col(E)]; late = H0(256N)
    //   then A(96N) | B(96N) | C(96N)
    float* ws     = (float*)d_ws;
    float* H0     = ws;
    int*   rowptr = (int*)d_ws;
    int*   cursor = rowptr + (N + 1);
    int*   col    = cursor + N;
    float* A      = ws + (size_t)256 * N;
    float* B      = A + (size_t)96 * N;
    float* C      = B + (size_t)96 * N;

    const dim3 blk(NB);
    const int rt64 = (N + 63) / 64;
    const dim3 gE((E + NB - 1) / NB);
    const dim3 gGather(((size_t)N * 24 + NB - 1) / NB);

    // ---- CSR build ----
    hipMemsetAsync(cursor, 0, (size_t)N * sizeof(int), stream);
    count_int_kernel<<<gE, blk, 0, stream>>>(dst, cursor, E);
    scan_kernel<<<dim3(1), dim3(1024), 0, stream>>>(cursor, rowptr, cursor, N);
    fill_csr_kernel<<<gE, blk, 0, stream>>>(src, dst, cursor, col, E);

    // ---- embed + lin -> A (embedding fused; K=80 -> BK=16) ----
    gemm_mfma<80, 96, 3, 16, false, false, true, false>
        <<<dim3(rt64), blk, 0, stream>>>(
        nullptr, nullptr, lin_W, nullptr, lin_b,
        x_layout, x_role, lemb, remb, nullptr, nullptr, A, N);

    // ---- layer 0: A -> C ----
    gather_mean_kernel<<<gGather, blk, 0, stream>>>(A, rowptr, col, B, N);
    gemm_mfma<96, 96, 3, 32, true, true, false, false>
        <<<dim3(rt64), blk, 0, stream>>>(
        A, B, c0_rW, c0_lW, c0_lb, nullptr, nullptr, nullptr, nullptr,
        nullptr, nullptr, C, N);

    // ---- layer 1: C -> A ----
    gather_mean_kernel<<<gGather, blk, 0, stream>>>(C, rowptr, col, B, N);
    gemm_mfma<96, 96, 3, 32, true, true, false, false>
        <<<dim3(rt64), blk, 0, stream>>>(
        C, B, c1_rW, c1_lW, c1_lb, nullptr, nullptr, nullptr, nullptr,
        nullptr, nullptr, A, N);

    // ---- layer 2: A -> C ----
    gather_mean_kernel<<<gGather, blk, 0, stream>>>(A, rowptr, col, B, N);
    gemm_mfma<96, 96, 3, 32, true, true, false, false>
        <<<dim3(rt64), blk, 0, stream>>>(
        A, B, c2_rW, c2_lW, c2_lb, nullptr, nullptr, nullptr, nullptr,
        nullptr, nullptr, C, N);

    // ---- head: d0 (C -> H0), then d1+d2 fused (H0 -> out) ----
    gemm_mfma<96, 256, 4, 32, true, false, false, false>
        <<<dim3(rt64 * 2), blk, 0, stream>>>(
        C, nullptr, d0_W, nullptr, d0_b, nullptr, nullptr, nullptr, nullptr,
        nullptr, nullptr, H0, N);

    hipMemsetAsync(d_out, 0, (size_t)N * sizeof(float), stream);
    gemm_mfma<256, 256, 4, 32, true, false, false, true>
        <<<dim3(rt64 * 2), blk, 0, stream>>>(
        H0, nullptr, d1_W, nullptr, d1_b, nullptr, nullptr, nullptr, nullptr,
        d2_W, d2_b, (float*)d_out, N);
}

// Round 12
// 499.515 us; speedup vs baseline: 4.4955x; 1.1324x over previous
//
#include <hip/hip_runtime.h>
#include <cstddef>

// ---------------------------------------------------------------------------
// embed+concat -> Linear(80->96) -> 3x SAGEConv(96, mean) -> MLP(96->256->256->1)
// fp32 in/out. N = in_sizes[1], E = in_sizes[2]/2.
// Round 12: replace single-block Hillis-Steele scan (76 us, 1 CU) with a
// 3-kernel multi-block shuffle scan (~10 us). MFMA GEMMs (r11) unchanged.
// ---------------------------------------------------------------------------

#define NB 256

using f16x4 = __attribute__((ext_vector_type(4))) _Float16;
using f32x4 = __attribute__((ext_vector_type(4))) float;

// ---- CSR: count in-degree --------------------------------------------------
__global__ __launch_bounds__(NB) void count_int_kernel(const int* __restrict__ dst,
                                                       int* __restrict__ cnt, int E) {
    int e = blockIdx.x * NB + threadIdx.x;
    if (e < E) atomicAdd(&cnt[dst[e]], 1);
}

// ---- multi-block scan, stage 1: per-block (2048 elems) sums ----------------
__global__ __launch_bounds__(NB) void scan_part1(const int* __restrict__ cnt,
                                                 int* __restrict__ part, int n) {
    __shared__ int ws[4];
    const int tid = threadIdx.x;
    const int base = blockIdx.x * 2048 + tid * 8;
    int s = 0;
#pragma unroll
    for (int q = 0; q < 8; ++q) {
        int i = base + q;
        if (i < n) s += cnt[i];
    }
#pragma unroll
    for (int off = 1; off < 64; off <<= 1) s += __shfl_xor(s, off);
    if ((tid & 63) == 0) ws[tid >> 6] = s;
    __syncthreads();
    if (tid == 0) part[blockIdx.x] = ws[0] + ws[1] + ws[2] + ws[3];
}

// ---- stage 2: single-wave exclusive scan of partials (nb <= 64) ------------
__global__ __launch_bounds__(64) void scan_part2(int* __restrict__ part,
                                                 int* __restrict__ rowptr,
                                                 int nb, int n) {
    const int lane = threadIdx.x;
    int v = (lane < nb) ? part[lane] : 0;
    int incl = v;
#pragma unroll
    for (int off = 1; off < 64; off <<= 1) {
        int u = __shfl_up(incl, off);
        if (lane >= off) incl += u;
    }
    if (lane < nb) part[lane] = incl - v;   // exclusive block offset
    if (lane == 63) rowptr[n] = incl;       // grand total
}

// ---- stage 3: per-block local scan + global offset -> rowptr & cursor ------
__global__ __launch_bounds__(NB) void scan_part3(const int* __restrict__ cnt,
                                                 const int* __restrict__ part,
                                                 int* __restrict__ rowptr,
                                                 int* __restrict__ cursor, int n) {
    __shared__ int ws[4];
    const int tid = threadIdx.x;
    const int lane = tid & 63, w = tid >> 6;
    const int base = blockIdx.x * 2048 + tid * 8;
    int loc[8];
    int s = 0;
#pragma unroll
    for (int q = 0; q < 8; ++q) {
        int i = base + q;
        int v = (i < n) ? cnt[i] : 0;
        loc[q] = s;
        s += v;
    }
    int incl = s;
#pragma unroll
    for (int off = 1; off < 64; off <<= 1) {
        int u = __shfl_up(incl, off);
        if (lane >= off) incl += u;
    }
    if (lane == 63) ws[w] = incl;
    __syncthreads();
    int woff = 0;
    for (int i = 0; i < w; ++i) woff += ws[i];
    int gbase = part[blockIdx.x] + woff + (incl - s);
#pragma unroll
    for (int q = 0; q < 8; ++q) {
        int i = base + q;
        if (i < n) {
            int v = gbase + loc[q];
            rowptr[i] = v;
            cursor[i] = v;
        }
    }
}

// ---- CSR: fill column (src) list -------------------------------------------
__global__ __launch_bounds__(NB) void fill_csr_kernel(const int* __restrict__ src,
                                                      const int* __restrict__ dst,
                                                      int* __restrict__ cursor,
                                                      int* __restrict__ col, int E) {
    int e = blockIdx.x * NB + threadIdx.x;
    if (e >= E) return;
    int p = atomicAdd(&cursor[dst[e]], 1);
    col[p] = src[e];
}

// ---- gather-mean: G[n] = mean_{j in col[rowptr[n]:rowptr[n+1]]} X[j] -------
__global__ __launch_bounds__(NB) void gather_mean_kernel(
    const float* __restrict__ X, const int* __restrict__ rowptr,
    const int* __restrict__ col, float* __restrict__ G, int N) {
    int idx = blockIdx.x * NB + threadIdx.x;
    int node = idx / 24;
    if (node >= N) return;
    int c = idx - node * 24;
    const int s = rowptr[node], pe = rowptr[node + 1];
    float4 acc = {0.f, 0.f, 0.f, 0.f};
    int p = s;
    for (; p + 3 < pe; p += 4) {
        int j0 = col[p], j1 = col[p + 1], j2 = col[p + 2], j3 = col[p + 3];
        float4 v0 = *reinterpret_cast<const float4*>(&X[(size_t)j0 * 96 + 4 * c]);
        float4 v1 = *reinterpret_cast<const float4*>(&X[(size_t)j1 * 96 + 4 * c]);
        float4 v2 = *reinterpret_cast<const float4*>(&X[(size_t)j2 * 96 + 4 * c]);
        float4 v3 = *reinterpret_cast<const float4*>(&X[(size_t)j3 * 96 + 4 * c]);
        acc.x += (v0.x + v1.x) + (v2.x + v3.x);
        acc.y += (v0.y + v1.y) + (v2.y + v3.y);
        acc.z += (v0.z + v1.z) + (v2.z + v3.z);
        acc.w += (v0.w + v1.w) + (v2.w + v3.w);
    }
    for (; p < pe; ++p) {
        int j = col[p];
        float4 v = *reinterpret_cast<const float4*>(&X[(size_t)j * 96 + 4 * c]);
        acc.x += v.x; acc.y += v.y; acc.z += v.z; acc.w += v.w;
    }
    int deg = pe - s;
    float inv = (deg > 0) ? 1.f / (float)deg : 0.f;
    acc.x *= inv; acc.y *= inv; acc.z *= inv; acc.w *= inv;
    *reinterpret_cast<float4*>(&G[(size_t)node * 96 + 4 * c]) = acc;
}

// ---- fp32 -> (hi, lo) f16 split --------------------------------------------
__device__ inline void cvt_split(float4 f, f16x4& hi, f16x4& lo) {
    _Float16 h0 = (_Float16)f.x, h1 = (_Float16)f.y;
    _Float16 h2 = (_Float16)f.z, h3 = (_Float16)f.w;
    hi = (f16x4){h0, h1, h2, h3};
    lo = (f16x4){(_Float16)(f.x - (float)h0), (_Float16)(f.y - (float)h1),
                 (_Float16)(f.z - (float)h2), (_Float16)(f.w - (float)h3)};
}

// ---- MFMA GEMM: Y = act(X @ Wx^T [+ G @ Wg^T] + bias) ----------------------
// fp16-split: acc += Ahi*Bhi + Ahi*Blo + Alo*Bhi (lo*lo dropped, ~2^-22).
// v_mfma_f32_16x16x16f16 layouts: A row=lane&15, k=4*(lane>>4)+j; B col same;
// D col=lane&15, row=4*(lane>>4)+j. 4 waves (2x2), wave = 32 rows x TC tiles.
template <int K, int OUT, int TC, int BK, bool RELU, bool SAGE, bool EMB, bool FDOT>
__global__ __launch_bounds__(NB) void gemm_mfma(
    const float* __restrict__ X, const float* __restrict__ G,
    const float* __restrict__ Wx, const float* __restrict__ Wg,
    const float* __restrict__ bias,
    const int* __restrict__ xl, const int* __restrict__ xr,
    const float* __restrict__ lemb, const float* __restrict__ remb,
    const float* __restrict__ d2w, const float* __restrict__ d2b,
    float* __restrict__ Y, int nrows) {
    constexpr int BM = 64;
    constexpr int BN = 2 * TC * 16;
    constexpr int CT = OUT / BN;
    constexpr int KT = SAGE ? 2 * K : K;
    constexpr int QX = BK / 4;
    constexpr int ST = BK + 4;
    __shared__ alignas(16) _Float16 Xhi[BM][ST];
    __shared__ alignas(16) _Float16 Xlo[BM][ST];
    __shared__ alignas(16) _Float16 Whi[BN][ST];
    __shared__ alignas(16) _Float16 Wlo[BN][ST];

    const int t = threadIdx.x;
    const int lane = t & 63;
    const int wave = t >> 6;
    const int lm = lane & 15, lg = lane >> 4;
    const int wm = (wave >> 1) * 32;
    const int wn = (wave & 1) * (TC * 16);

    const int bid = blockIdx.x;
    const int rowBase = (bid / CT) * BM;
    const int colTile = bid % CT;
    const int colBase = colTile * BN;

    f32x4 acc[2][TC];
#pragma unroll
    for (int tr = 0; tr < 2; ++tr)
#pragma unroll
        for (int tc = 0; tc < TC; ++tc) acc[tr][tc] = (f32x4){0.f, 0.f, 0.f, 0.f};

    for (int k0 = 0; k0 < KT; k0 += BK) {
        const bool isG = SAGE && (k0 >= K);
        const float* __restrict__ Xp = isG ? G : X;
        const float* __restrict__ Wp = isG ? Wg : Wx;
        const int kl = isG ? (k0 - K) : k0;

        for (int v = t; v < BM * QX; v += NB) {
            int q = v % QX, m = v / QX;
            int r = rowBase + m;
            float4 f = {0.f, 0.f, 0.f, 0.f};
            if (r < nrows) {
                if (EMB) {
                    int kk = kl + 4 * q;
                    if (kk < 64) {
                        int l = kk >> 4, c = kk & 15;
                        f = *reinterpret_cast<const float4*>(
                            &lemb[(size_t)xl[r * 4 + l] * 16 + c]);
                    } else {
                        f = *reinterpret_cast<const float4*>(
                            &remb[(size_t)xr[r] * 16 + (kk - 64)]);
                    }
                } else {
                    f = *reinterpret_cast<const float4*>(&Xp[(size_t)r * K + kl + 4 * q]);
                }
            }
            f16x4 hi, lo;
            cvt_split(f, hi, lo);
            *reinterpret_cast<f16x4*>(&Xhi[m][4 * q]) = hi;
            *reinterpret_cast<f16x4*>(&Xlo[m][4 * q]) = lo;
        }
        for (int v = t; v < BN * QX; v += NB) {
            int q = v % QX, n = v / QX;
            float4 f = *reinterpret_cast<const float4*>(
                &Wp[(size_t)(colBase + n) * K + kl + 4 * q]);
            f16x4 hi, lo;
            cvt_split(f, hi, lo);
            *reinterpret_cast<f16x4*>(&Whi[n][4 * q]) = hi;
            *reinterpret_cast<f16x4*>(&Wlo[n][4 * q]) = lo;
        }
        __syncthreads();

#pragma unroll
        for (int g = 0; g < BK / 16; ++g) {
            f16x4 ah[2], al[2], bh[TC], bl[TC];
#pragma unroll
            for (int tr = 0; tr < 2; ++tr) {
                ah[tr] = *reinterpret_cast<const f16x4*>(
                    &Xhi[wm + tr * 16 + lm][g * 16 + 4 * lg]);
                al[tr] = *reinterpret_cast<const f16x4*>(
                    &Xlo[wm + tr * 16 + lm][g * 16 + 4 * lg]);
            }
#pragma unroll
            for (int tc = 0; tc < TC; ++tc) {
                bh[tc] = *reinterpret_cast<const f16x4*>(
                    &Whi[wn + tc * 16 + lm][g * 16 + 4 * lg]);
                bl[tc] = *reinterpret_cast<const f16x4*>(
                    &Wlo[wn + tc * 16 + lm][g * 16 + 4 * lg]);
            }
#pragma unroll
            for (int tr = 0; tr < 2; ++tr)
#pragma unroll
                for (int tc = 0; tc < TC; ++tc) {
                    acc[tr][tc] = __builtin_amdgcn_mfma_f32_16x16x16f16(
                        ah[tr], bh[tc], acc[tr][tc], 0, 0, 0);
                    acc[tr][tc] = __builtin_amdgcn_mfma_f32_16x16x16f16(
                        ah[tr], bl[tc], acc[tr][tc], 0, 0, 0);
                    acc[tr][tc] = __builtin_amdgcn_mfma_f32_16x16x16f16(
                        al[tr], bh[tc], acc[tr][tc], 0, 0, 0);
                }
        }
        __syncthreads();
    }

    if (!FDOT) {
#pragma unroll
        for (int tr = 0; tr < 2; ++tr)
#pragma unroll
            for (int tc = 0; tc < TC; ++tc) {
                int c = colBase + wn + tc * 16 + lm;
#pragma unroll
                for (int j = 0; j < 4; ++j) {
                    int r = rowBase + wm + tr * 16 + 4 * lg + j;
                    if (r >= nrows) continue;
                    float v = acc[tr][tc][j] + bias[c];
                    if (RELU) v = fmaxf(v, 0.f);
                    Y[(size_t)r * OUT + c] = v;
                }
            }
    } else {
#pragma unroll
        for (int tr = 0; tr < 2; ++tr) {
            float p[4] = {0.f, 0.f, 0.f, 0.f};
#pragma unroll
            for (int tc = 0; tc < TC; ++tc) {
                int c = colBase + wn + tc * 16 + lm;
                float bv = bias[c];
                float dw = d2w[c];
#pragma unroll
                for (int j = 0; j < 4; ++j) {
                    float v = fmaxf(acc[tr][tc][j] + bv, 0.f);
                    p[j] += v * dw;
                }
            }
#pragma unroll
            for (int j = 0; j < 4; ++j) {
                float s = p[j];
#pragma unroll
                for (int off = 1; off < 16; off <<= 1) s += __shfl_xor(s, off);
                int r = rowBase + wm + tr * 16 + 4 * lg + j;
                if (lm == 0 && r < nrows) {
                    float extra = (colTile == 0 && wn == 0) ? d2b[0] : 0.f;
                    atomicAdd(&Y[r], s + extra);
                }
            }
        }
    }
}

// ---------------------------------------------------------------------------
extern "C" void kernel_launch(void* const* d_in, const int* in_sizes, int n_in,
                              void* d_out, int out_size, void* d_ws, size_t ws_size,
                              hipStream_t stream) {
    const int*   x_layout = (const int*)d_in[0];
    const int*   x_role   = (const int*)d_in[1];
    const int*   ei       = (const int*)d_in[2];
    const float* lemb     = (const float*)d_in[3];
    const float* remb     = (const float*)d_in[4];
    const float* lin_W    = (const float*)d_in[5];
    const float* lin_b    = (const float*)d_in[6];
    const float* c0_lW    = (const float*)d_in[7];
    const float* c0_lb    = (const float*)d_in[8];
    const float* c0_rW    = (const float*)d_in[9];
    const float* c1_lW    = (const float*)d_in[10];
    const float* c1_lb    = (const float*)d_in[11];
    const float* c1_rW    = (const float*)d_in[12];
    const float* c2_lW    = (const float*)d_in[13];
    const float* c2_lb    = (const float*)d_in[14];
    const float* c2_rW    = (const float*)d_in[15];
    const float* d0_W     = (const float*)d_in[16];
    const float* d0_b     = (const float*)d_in[17];
    const float* d1_W     = (const float*)d_in[18];
    const float* d1_b     = (const float*)d_in[19];
    const float* d2_W     = (const float*)d_in[20];
    const float* d2_b     = (const float*)d_in[21];

    const int N = in_sizes[1];
    const int E = in_sizes[2] / 2;
    const int* src = ei;
    const int* dst = ei + E;

    // workspace (4-byte elems):
    //   R0 (256N): early = [rowptr(N+1)|cursor(N)|col(E)|part(64)]; late = H0
    //   then A(96N) | B(96N) | C(96N)
    float* ws     = (float*)d_ws;
    float* H0     = ws;
    int*   rowptr = (int*)d_ws;
    int*   cursor = rowptr + (N + 1);
    int*   col    = cursor + N;
    int*   part   = col + E;
    float* A      = ws + (size_t)256 * N;
    float* B      = A + (size_t)96 * N;
    float* C      = B + (size_t)96 * N;

    const dim3 blk(NB);
    const int rt64 = (N + 63) / 64;
    const int nbScan = (N + 2047) / 2048;   // <= 64 for N <= 131072
    const dim3 gE((E + NB - 1) / NB);
    const dim3 gGather(((size_t)N * 24 + NB - 1) / NB);

    // ---- CSR build (multi-block scan) ----
    hipMemsetAsync(cursor, 0, (size_t)N * sizeof(int), stream);
    count_int_kernel<<<gE, blk, 0, stream>>>(dst, cursor, E);
    scan_part1<<<dim3(nbScan), blk, 0, stream>>>(cursor, part, N);
    scan_part2<<<dim3(1), dim3(64), 0, stream>>>(part, rowptr, nbScan, N);
    scan_part3<<<dim3(nbScan), blk, 0, stream>>>(cursor, part, rowptr, cursor, N);
    fill_csr_kernel<<<gE, blk, 0, stream>>>(src, dst, cursor, col, E);

    // ---- embed + lin -> A (embedding fused; K=80 -> BK=16) ----
    gemm_mfma<80, 96, 3, 16, false, false, true, false>
        <<<dim3(rt64), blk, 0, stream>>>(
        nullptr, nullptr, lin_W, nullptr, lin_b,
        x_layout, x_role, lemb, remb, nullptr, nullptr, A, N);

    // ---- layer 0: A -> C ----
    gather_mean_kernel<<<gGather, blk, 0, stream>>>(A, rowptr, col, B, N);
    gemm_mfma<96, 96, 3, 32, true, true, false, false>
        <<<dim3(rt64), blk, 0, stream>>>(
        A, B, c0_rW, c0_lW, c0_lb, nullptr, nullptr, nullptr, nullptr,
        nullptr, nullptr, C, N);

    // ---- layer 1: C -> A ----
    gather_mean_kernel<<<gGather, blk, 0, stream>>>(C, rowptr, col, B, N);
    gemm_mfma<96, 96, 3, 32, true, true, false, false>
        <<<dim3(rt64), blk, 0, stream>>>(
        C, B, c1_rW, c1_lW, c1_lb, nullptr, nullptr, nullptr, nullptr,
        nullptr, nullptr, A, N);

    // ---- layer 2: A -> C ----
    gather_mean_kernel<<<gGather, blk, 0, stream>>>(A, rowptr, col, B, N);
    gemm_mfma<96, 96, 3, 32, true, true, false, false>
        <<<dim3(rt64), blk, 0, stream>>>(
        A, B, c2_rW, c2_lW, c2_lb, nullptr, nullptr, nullptr, nullptr,
        nullptr, nullptr, C, N);

    // ---- head: d0 (C -> H0), then d1+d2 fused (H0 -> out) ----
    gemm_mfma<96, 256, 4, 32, true, false, false, false>
        <<<dim3(rt64 * 2), blk, 0, stream>>>(
        C, nullptr, d0_W, nullptr, d0_b, nullptr, nullptr, nullptr, nullptr,
        nullptr, nullptr, H0, N);

    hipMemsetAsync(d_out, 0, (size_t)N * sizeof(float), stream);
    gemm_mfma<256, 256, 4, 32, true, false, false, true>
        <<<dim3(rt64 * 2), blk, 0, stream>>>(
        H0, nullptr, d1_W, nullptr, d1_b, nullptr, nullptr, nullptr, nullptr,
        d2_W, d2_b, (float*)d_out, N);
}